// Round 7
// baseline (463.879 us; speedup 1.0000x reference)
//
#include <hip/hip_runtime.h>

constexpr int N = 50000;    // nodes
constexpr int E = 800000;   // edges
constexpr int NPAD = 50048; // padded row count (64-multiple)
constexpr int NB = (N + 255) / 256;

typedef _Float16 half8 __attribute__((ext_vector_type(8)));
typedef _Float16 half4v __attribute__((ext_vector_type(4)));
typedef float float4v __attribute__((ext_vector_type(4)));

// ---------------- degree / normalization / CSR ----------------
__global__ __launch_bounds__(256) void deg_kernel(const int* __restrict__ dst,
                                                  int* __restrict__ degI) {
    int e = blockIdx.x * 256 + threadIdx.x;
    if (e < E) atomicAdd(&degI[dst[e]], 1);
}

__global__ __launch_bounds__(256) void dinv_kernel(const int* __restrict__ degI,
                                                   float* __restrict__ dinv) {
    int v = blockIdx.x * 256 + threadIdx.x;
    if (v < N) dinv[v] = rsqrtf((float)degI[v] + 1.0f);
}

__global__ __launch_bounds__(256) void scan1_kernel(const int* __restrict__ degI,
                                                    int* __restrict__ incl,
                                                    int* __restrict__ blockSums) {
    __shared__ int s[256];
    int t = threadIdx.x;
    int i = blockIdx.x * 256 + t;
    int d = (i < N) ? degI[i] : 0;
    s[t] = d;
    __syncthreads();
    for (int off = 1; off < 256; off <<= 1) {
        int v = s[t];
        int u = (t >= off) ? s[t - off] : 0;
        __syncthreads();
        s[t] = v + u;
        __syncthreads();
    }
    if (i < N) incl[i] = s[t];
    if (t == 255) blockSums[blockIdx.x] = s[255];
}

__global__ __launch_bounds__(256) void scan2_kernel(int* __restrict__ blockSums) {
    __shared__ int s[256];
    int t = threadIdx.x;
    int v = (t < NB) ? blockSums[t] : 0;
    s[t] = v;
    __syncthreads();
    for (int off = 1; off < 256; off <<= 1) {
        int a = s[t];
        int u = (t >= off) ? s[t - off] : 0;
        __syncthreads();
        s[t] = a + u;
        __syncthreads();
    }
    if (t < NB) blockSums[t] = s[t] - v;
}

__global__ __launch_bounds__(256) void scan3_kernel(const int* __restrict__ degI,
                                                    const int* __restrict__ incl,
                                                    const int* __restrict__ blockSums,
                                                    int* __restrict__ rowptr,
                                                    int* __restrict__ cursor) {
    int i = blockIdx.x * 256 + threadIdx.x;
    if (i < N) {
        int e = blockSums[blockIdx.x] + incl[i] - degI[i];
        rowptr[i] = e;
        cursor[i] = e;
    }
    if (i == 0) rowptr[N] = E;
}

__global__ __launch_bounds__(256) void fill_kernel(const int* __restrict__ src,
                                                   const int* __restrict__ dst,
                                                   int* __restrict__ cursor,
                                                   int* __restrict__ eidx) {
    int e = blockIdx.x * 256 + threadIdx.x;
    if (e >= E) return;
    int d = dst[e];
    int pos = atomicAdd(&cursor[d], 1);
    eidx[pos] = src[e];
}

// ---------------- weight transpose+cast: Wt[n][k] = (f16) W[k][n] ----------------
template <int K>
__global__ __launch_bounds__(256) void wt_kernel(const float* __restrict__ W,
                                                 _Float16* __restrict__ Wt) {
    int idx = blockIdx.x * 256 + threadIdx.x;
    int k = idx & (K - 1);
    int n = idx >> (K == 128 ? 7 : 8);
    Wt[idx] = (_Float16)W[(size_t)k * 256 + n];
}

// ---------------- prescale -> 16-ch slice-major fp16 ----------------
// px[s][v][16] with s = c>>4;  source x row-major [N,128] fp32
__global__ __launch_bounds__(256) void prescale_kernel(const float4* __restrict__ x,
                                                       const float* __restrict__ dinv,
                                                       half4v* __restrict__ px) {
    int idx = blockIdx.x * 256 + threadIdx.x;   // N*32 float4 units
    if (idx >= N * 32) return;
    int v = idx >> 5;
    int u = idx & 31;                // half4v unit: channels 4u..4u+3
    float dv = dinv[v];
    float4 t = x[idx];
    half4v o;
    o[0] = (_Float16)(t.x * dv);
    o[1] = (_Float16)(t.y * dv);
    o[2] = (_Float16)(t.z * dv);
    o[3] = (_Float16)(t.w * dv);
    int slice = u >> 2;              // (4u)>>4
    px[((size_t)slice * NPAD + v) * 4 + (u & 3)] = o;
}

// ---------------- sliced gather-aggregate ----------------
// f, q slice-major: slice stride NPAD*CH halves. 8 slices; slice = blockIdx&7 -> XCD.
// U = CH/8 lanes (half8 each) per node.
template <int CH>
__global__ __launch_bounds__(256) void aggregate_sl(
    const int* __restrict__ rowptr, const int* __restrict__ eidx,
    const half8* __restrict__ f, const float* __restrict__ dinv,
    half8* __restrict__ q) {
    constexpr int U = CH / 8;
    constexpr int NPB = 256 / U;
    int s = blockIdx.x & 7;
    int g = blockIdx.x >> 3;
    int v = g * NPB + threadIdx.x / U;
    if (v >= N) return;
    int lane = threadIdx.x % U;

    const half8* fs = f + (size_t)s * NPAD * U;   // this slice's table (L2-resident)
    int beg = rowptr[v];
    int end = rowptr[v + 1];

    half8 sv = fs[(size_t)v * U + lane];
    float a[8];
#pragma unroll
    for (int j = 0; j < 8; ++j) a[j] = (float)sv[j];

    int i = beg;
    for (; i + 1 < end; i += 2) {
        int s0 = __builtin_nontemporal_load(&eidx[i]);
        int s1 = __builtin_nontemporal_load(&eidx[i + 1]);
        half8 t0 = fs[(size_t)s0 * U + lane];
        half8 t1 = fs[(size_t)s1 * U + lane];
#pragma unroll
        for (int j = 0; j < 8; ++j) a[j] += (float)t0[j] + (float)t1[j];
    }
    if (i < end) {
        int s0 = __builtin_nontemporal_load(&eidx[i]);
        half8 t0 = fs[(size_t)s0 * U + lane];
#pragma unroll
        for (int j = 0; j < 8; ++j) a[j] += (float)t0[j];
    }

    float dv = dinv[v];
    half8 o;
#pragma unroll
    for (int j = 0; j < 8; ++j) o[j] = (_Float16)(a[j] * dv);
    __builtin_nontemporal_store(o, &q[(size_t)s * NPAD * U + (size_t)v * U + lane]);
}

// ---------------- fp16 MFMA GEMM, sliced-A, no LDS ----------------
// A slice-major [K/CH][NPAD][CH] f16; Wt row-major [256][K] f16.
// FUSE1: out = 32-ch slice-major f16 dinv*relu(D+bias); else fp32 row-major D+bias.
template <int K, int CH, bool FUSE1>
__global__ __launch_bounds__(256) void gemm_mfma(
    const _Float16* __restrict__ A, const _Float16* __restrict__ Wt,
    const float* __restrict__ bias, const float* __restrict__ dinv,
    void* __restrict__ outp) {
    int wave = threadIdx.x >> 6;
    int lane = threadIdx.x & 63;
    int m = lane & 15;
    int quad = lane >> 4;
    int rbase = blockIdx.x * 64 + wave * 16;
    int cbase = blockIdx.y * 64;

    float4v acc[4] = {};

    const half8* A8 = (const half8*)A;
    int r = rbase + m;
#pragma unroll
    for (int k0 = 0; k0 < K; k0 += 32) {
        int k_abs = k0 + quad * 8;
        int slice = k_abs / CH;
        int koffu = (k_abs % CH) >> 3;
        half8 a = A8[((size_t)slice * NPAD + r) * (CH / 8) + koffu];
#pragma unroll
        for (int c = 0; c < 4; ++c) {
            const half8* Brow = (const half8*)(Wt + (size_t)(cbase + c * 16 + m) * K);
            half8 b = Brow[(k0 >> 3) + quad];
            acc[c] = __builtin_amdgcn_mfma_f32_16x16x32_f16(a, b, acc[c], 0, 0, 0);
        }
    }

#pragma unroll
    for (int c = 0; c < 4; ++c) {
        int col = cbase + c * 16 + m;
        float bcol = bias[col];
#pragma unroll
        for (int rr = 0; rr < 4; ++rr) {
            int row = rbase + quad * 4 + rr;   // C/D: col=lane&15, row=quad*4+reg
            if (row < N) {
                float val = acc[c][rr] + bcol;
                if (FUSE1) {
                    val = fmaxf(val, 0.f) * dinv[row];
                    // 32-ch slice-major for layer-2 aggregate
                    ((_Float16*)outp)[((size_t)(col >> 5) * NPAD + row) * 32 + (col & 31)] =
                        (_Float16)val;
                } else {
                    ((float*)outp)[(size_t)row * 256 + col] = val;
                }
            }
        }
    }
}

extern "C" void kernel_launch(void* const* d_in, const int* in_sizes, int n_in,
                              void* d_out, int out_size, void* d_ws, size_t ws_size,
                              hipStream_t stream) {
    const float* x  = (const float*)d_in[0];
    const int* edge = (const int*)d_in[1];
    const int* src  = edge;
    const int* dst  = edge + E;
    const float* W1 = (const float*)d_in[2];
    const float* b1 = (const float*)d_in[3];
    const float* W2 = (const float*)d_in[4];
    const float* b2 = (const float*)d_in[5];
    float* out = (float*)d_out;

    _Float16* bufA = (_Float16*)d_ws;                 // px (16ch-sliced) -> h1p (32ch-sliced)
    _Float16* bufB = bufA + (size_t)NPAD * 256;       // q1 (16ch-sliced) -> q2 (32ch-sliced)
    float* dinv    = (float*)(bufB + (size_t)NPAD * 256);
    int* degI      = (int*)(dinv + N);
    int* rowptr    = degI + N;
    int* cursor    = rowptr + (N + 1);
    int* eidx      = cursor + N;
    _Float16* W1t  = (_Float16*)(eidx + E);
    _Float16* W2t  = W1t + 256 * 128;
    int* blockSums = (int*)(W2t + 256 * 256);

    // ---- CSR + normalization ----
    hipMemsetAsync(degI, 0, N * sizeof(int), stream);
    deg_kernel<<<(E + 255) / 256, 256, 0, stream>>>(dst, degI);
    dinv_kernel<<<(N + 255) / 256, 256, 0, stream>>>(degI, dinv);
    scan1_kernel<<<NB, 256, 0, stream>>>(degI, cursor, blockSums);
    scan2_kernel<<<1, 256, 0, stream>>>(blockSums);
    scan3_kernel<<<NB, 256, 0, stream>>>(degI, cursor, blockSums, rowptr, cursor);
    fill_kernel<<<(E + 255) / 256, 256, 0, stream>>>(src, dst, cursor, eidx);

    // ---- weights ----
    wt_kernel<128><<<(256 * 128) / 256, 256, 0, stream>>>(W1, W1t);
    wt_kernel<256><<<(256 * 256) / 256, 256, 0, stream>>>(W2, W2t);

    // ---- layer 1:  px -> q1 = Ahat px (16-ch slices) -> h1p = dinv*relu(q1@W1+b1) ----
    prescale_kernel<<<(N * 32 + 255) / 256, 256, 0, stream>>>(
        (const float4*)x, dinv, (half4v*)bufA);
    {
        constexpr int NPB = 256 / (16 / 8);            // 128 nodes/block
        int ngroups = (N + NPB - 1) / NPB;
        aggregate_sl<16><<<ngroups * 8, 256, 0, stream>>>(
            rowptr, eidx, (const half8*)bufA, dinv, (half8*)bufB);
    }
    gemm_mfma<128, 16, true><<<dim3(NPAD / 64, 4), 256, 0, stream>>>(
        bufB, W1t, b1, dinv, bufA);

    // ---- layer 2:  q2 = Ahat h1p (32-ch slices) -> out = q2@W2 + b2 ----
    {
        constexpr int NPB = 256 / (32 / 8);            // 64 nodes/block
        int ngroups = (N + NPB - 1) / NPB;
        aggregate_sl<32><<<ngroups * 8, 256, 0, stream>>>(
            rowptr, eidx, (const half8*)bufA, dinv, (half8*)bufB);
    }
    gemm_mfma<256, 32, false><<<dim3(NPAD / 64, 4), 256, 0, stream>>>(
        bufB, W2t, b2, dinv, out);
}

// Round 8
// 376.561 us; speedup vs baseline: 1.2319x; 1.2319x over previous
//
#include <hip/hip_runtime.h>

constexpr int N = 50000;    // nodes
constexpr int E = 800000;   // edges
constexpr int NPAD = 50048; // padded to 64-row multiple for GEMM A tiles
constexpr int NB = (N + 255) / 256;   // 196 scan blocks

typedef _Float16 half8 __attribute__((ext_vector_type(8)));
typedef _Float16 half4v __attribute__((ext_vector_type(4)));
typedef float float4v __attribute__((ext_vector_type(4)));

// ---------------- degree / normalization / CSR ----------------
__global__ __launch_bounds__(256) void deg_kernel(const int* __restrict__ dst,
                                                  int* __restrict__ degI) {
    int e = blockIdx.x * 256 + threadIdx.x;
    if (e < E) atomicAdd(&degI[dst[e]], 1);
}

__global__ __launch_bounds__(256) void dinv_kernel(const int* __restrict__ degI,
                                                   float* __restrict__ dinv) {
    int v = blockIdx.x * 256 + threadIdx.x;
    if (v < N) dinv[v] = rsqrtf((float)degI[v] + 1.0f);   // +1 = self loop
}

// ---- 3-phase scan ----
__global__ __launch_bounds__(256) void scan1_kernel(const int* __restrict__ degI,
                                                    int* __restrict__ incl,
                                                    int* __restrict__ blockSums) {
    __shared__ int s[256];
    int t = threadIdx.x;
    int i = blockIdx.x * 256 + t;
    int d = (i < N) ? degI[i] : 0;
    s[t] = d;
    __syncthreads();
    for (int off = 1; off < 256; off <<= 1) {
        int v = s[t];
        int u = (t >= off) ? s[t - off] : 0;
        __syncthreads();
        s[t] = v + u;
        __syncthreads();
    }
    if (i < N) incl[i] = s[t];
    if (t == 255) blockSums[blockIdx.x] = s[255];
}

__global__ __launch_bounds__(256) void scan2_kernel(int* __restrict__ blockSums) {
    __shared__ int s[256];
    int t = threadIdx.x;
    int v = (t < NB) ? blockSums[t] : 0;
    s[t] = v;
    __syncthreads();
    for (int off = 1; off < 256; off <<= 1) {
        int a = s[t];
        int u = (t >= off) ? s[t - off] : 0;
        __syncthreads();
        s[t] = a + u;
        __syncthreads();
    }
    if (t < NB) blockSums[t] = s[t] - v;   // exclusive block offset
}

__global__ __launch_bounds__(256) void scan3_kernel(const int* __restrict__ degI,
                                                    const int* __restrict__ incl,
                                                    const int* __restrict__ blockSums,
                                                    int* __restrict__ rowptr,
                                                    int* __restrict__ cursor) {
    int i = blockIdx.x * 256 + threadIdx.x;
    if (i < N) {
        int e = blockSums[blockIdx.x] + incl[i] - degI[i];
        rowptr[i] = e;
        cursor[i] = e;
    }
    if (i == 0) rowptr[N] = E;
}

__global__ __launch_bounds__(256) void fill_kernel(const int* __restrict__ src,
                                                   const int* __restrict__ dst,
                                                   int* __restrict__ cursor,
                                                   int* __restrict__ eidx) {
    int e = blockIdx.x * 256 + threadIdx.x;
    if (e >= E) return;
    int d = dst[e];
    int pos = atomicAdd(&cursor[d], 1);
    eidx[pos] = src[e];
}

// ---------------- weight transpose+cast: Wt[n][k] = (f16) W[k][n] ----------------
template <int K>
__global__ __launch_bounds__(256) void wt_kernel(const float* __restrict__ W,
                                                 _Float16* __restrict__ Wt) {
    int idx = blockIdx.x * 256 + threadIdx.x;
    int k = idx & (K - 1);
    int n = idx >> (K == 128 ? 7 : 8);
    Wt[idx] = (_Float16)W[(size_t)k * 256 + n];
}

// ---------------- prescale: px = dinv[v] * x   (fp32 -> fp16, 128 ch) ----------------
__global__ __launch_bounds__(256) void prescale_kernel(const float4* __restrict__ x,
                                                       const float* __restrict__ dinv,
                                                       half4v* __restrict__ px) {
    int idx = blockIdx.x * 256 + threadIdx.x;
    if (idx >= N * 32) return;
    float dv = dinv[idx >> 5];
    float4 t = x[idx];
    half4v o;
    o[0] = (_Float16)(t.x * dv);
    o[1] = (_Float16)(t.y * dv);
    o[2] = (_Float16)(t.z * dv);
    o[3] = (_Float16)(t.w * dv);
    px[idx] = o;
}

// ---------------- gather-aggregate, 8-way MLP unroll (fp16 rows, fp32 accum) ------
// q[v] = (f16) dinv[v] * ( f[v] + sum_{u->v} f[u] ),  C4 = channels/4 (32 or 64).
// 8 edge indices loaded up front, 8 independent row-gathers in flight per wave.
template <int C4>
__global__ __launch_bounds__(256) void aggregate_f16(
    const int* __restrict__ rowptr, const int* __restrict__ eidx,
    const half4v* __restrict__ f, const float* __restrict__ dinv,
    half4v* __restrict__ q) {
    int v = blockIdx.x * (256 / C4) + threadIdx.x / C4;
    if (v >= N) return;
    int lane = threadIdx.x % C4;
    int beg = rowptr[v];
    int end = rowptr[v + 1];

    half4v sv = f[(size_t)v * C4 + lane];
    float a0 = (float)sv[0], a1 = (float)sv[1], a2 = (float)sv[2], a3 = (float)sv[3];

    int i = beg;
    for (; i + 8 <= end; i += 8) {
        int e0 = eidx[i + 0], e1 = eidx[i + 1], e2 = eidx[i + 2], e3 = eidx[i + 3];
        int e4 = eidx[i + 4], e5 = eidx[i + 5], e6 = eidx[i + 6], e7 = eidx[i + 7];
        half4v t0 = f[(size_t)e0 * C4 + lane];
        half4v t1 = f[(size_t)e1 * C4 + lane];
        half4v t2 = f[(size_t)e2 * C4 + lane];
        half4v t3 = f[(size_t)e3 * C4 + lane];
        half4v t4 = f[(size_t)e4 * C4 + lane];
        half4v t5 = f[(size_t)e5 * C4 + lane];
        half4v t6 = f[(size_t)e6 * C4 + lane];
        half4v t7 = f[(size_t)e7 * C4 + lane];
        a0 += ((float)t0[0] + (float)t1[0]) + ((float)t2[0] + (float)t3[0]) +
              ((float)t4[0] + (float)t5[0]) + ((float)t6[0] + (float)t7[0]);
        a1 += ((float)t0[1] + (float)t1[1]) + ((float)t2[1] + (float)t3[1]) +
              ((float)t4[1] + (float)t5[1]) + ((float)t6[1] + (float)t7[1]);
        a2 += ((float)t0[2] + (float)t1[2]) + ((float)t2[2] + (float)t3[2]) +
              ((float)t4[2] + (float)t5[2]) + ((float)t6[2] + (float)t7[2]);
        a3 += ((float)t0[3] + (float)t1[3]) + ((float)t2[3] + (float)t3[3]) +
              ((float)t4[3] + (float)t5[3]) + ((float)t6[3] + (float)t7[3]);
    }
    for (; i + 2 <= end; i += 2) {
        int e0 = eidx[i], e1 = eidx[i + 1];
        half4v t0 = f[(size_t)e0 * C4 + lane];
        half4v t1 = f[(size_t)e1 * C4 + lane];
        a0 += (float)t0[0] + (float)t1[0];
        a1 += (float)t0[1] + (float)t1[1];
        a2 += (float)t0[2] + (float)t1[2];
        a3 += (float)t0[3] + (float)t1[3];
    }
    if (i < end) {
        half4v t0 = f[(size_t)eidx[i] * C4 + lane];
        a0 += (float)t0[0];
        a1 += (float)t0[1];
        a2 += (float)t0[2];
        a3 += (float)t0[3];
    }

    float dv = dinv[v];
    half4v o;
    o[0] = (_Float16)(a0 * dv);
    o[1] = (_Float16)(a1 * dv);
    o[2] = (_Float16)(a2 * dv);
    o[3] = (_Float16)(a3 * dv);
    q[(size_t)v * C4 + lane] = o;
}

// ---------------- fp16 MFMA GEMM, no LDS (row-major A) ----------------
template <int K, bool FUSE1>
__global__ __launch_bounds__(256) void gemm_mfma(
    const _Float16* __restrict__ A, const _Float16* __restrict__ Wt,
    const float* __restrict__ bias, const float* __restrict__ dinv,
    void* __restrict__ outp) {
    int wave = threadIdx.x >> 6;
    int lane = threadIdx.x & 63;
    int m = lane & 15;
    int quad = lane >> 4;
    int rbase = blockIdx.x * 64 + wave * 16;
    int cbase = blockIdx.y * 64;

    float4v acc[4] = {};

    const half8* Arow = (const half8*)(A + (size_t)(rbase + m) * K);
#pragma unroll
    for (int k0 = 0; k0 < K; k0 += 32) {
        half8 a = Arow[(k0 >> 3) + quad];
#pragma unroll
        for (int c = 0; c < 4; ++c) {
            const half8* Brow = (const half8*)(Wt + (size_t)(cbase + c * 16 + m) * K);
            half8 b = Brow[(k0 >> 3) + quad];
            acc[c] = __builtin_amdgcn_mfma_f32_16x16x32_f16(a, b, acc[c], 0, 0, 0);
        }
    }

#pragma unroll
    for (int c = 0; c < 4; ++c) {
        int col = cbase + c * 16 + m;
        float bcol = bias[col];
#pragma unroll
        for (int r = 0; r < 4; ++r) {
            int row = rbase + quad * 4 + r;   // C/D: col=lane&15, row=quad*4+reg
            if (row < N) {
                float val = acc[c][r] + bcol;
                if (FUSE1) {
                    val = fmaxf(val, 0.f) * dinv[row];
                    ((_Float16*)outp)[(size_t)row * 256 + col] = (_Float16)val;
                } else {
                    ((float*)outp)[(size_t)row * 256 + col] = val;
                }
            }
        }
    }
}

extern "C" void kernel_launch(void* const* d_in, const int* in_sizes, int n_in,
                              void* d_out, int out_size, void* d_ws, size_t ws_size,
                              hipStream_t stream) {
    const float* x  = (const float*)d_in[0];
    const int* edge = (const int*)d_in[1];
    const int* src  = edge;
    const int* dst  = edge + E;
    const float* W1 = (const float*)d_in[2];
    const float* b1 = (const float*)d_in[3];
    const float* W2 = (const float*)d_in[4];
    const float* b2 = (const float*)d_in[5];
    float* out = (float*)d_out;

    _Float16* bufA = (_Float16*)d_ws;
    _Float16* bufB = bufA + (size_t)NPAD * 256;
    float* dinv    = (float*)(bufB + (size_t)NPAD * 256);
    int* degI      = (int*)(dinv + N);
    int* rowptr    = degI + N;
    int* cursor    = rowptr + (N + 1);
    int* eidx      = cursor + N;
    _Float16* W1t  = (_Float16*)(eidx + E);
    _Float16* W2t  = W1t + 256 * 128;
    int* blockSums = (int*)(W2t + 256 * 256);

    // ---- CSR + normalization ----
    hipMemsetAsync(degI, 0, N * sizeof(int), stream);
    deg_kernel<<<(E + 255) / 256, 256, 0, stream>>>(dst, degI);
    dinv_kernel<<<(N + 255) / 256, 256, 0, stream>>>(degI, dinv);
    scan1_kernel<<<NB, 256, 0, stream>>>(degI, cursor, blockSums);
    scan2_kernel<<<1, 256, 0, stream>>>(blockSums);
    scan3_kernel<<<NB, 256, 0, stream>>>(degI, cursor, blockSums, rowptr, cursor);
    fill_kernel<<<(E + 255) / 256, 256, 0, stream>>>(src, dst, cursor, eidx);

    // ---- weights to f16 transposed ----
    wt_kernel<128><<<(256 * 128) / 256, 256, 0, stream>>>(W1, W1t);
    wt_kernel<256><<<(256 * 256) / 256, 256, 0, stream>>>(W2, W2t);

    // ---- layer 1:  q1 = Ahat x (aggregate first), h1p = dinv*relu(q1@W1+b1) ----
    prescale_kernel<<<(N * 32 + 255) / 256, 256, 0, stream>>>(
        (const float4*)x, dinv, (half4v*)bufA);
    aggregate_f16<32><<<(N + 7) / 8, 256, 0, stream>>>(
        rowptr, eidx, (const half4v*)bufA, dinv, (half4v*)bufB);
    gemm_mfma<128, true><<<dim3(NPAD / 64, 4), 256, 0, stream>>>(
        bufB, W1t, b1, dinv, bufA);

    // ---- layer 2:  q2 = Ahat h1, out = q2@W2 + b2 ----
    aggregate_f16<64><<<(N + 3) / 4, 256, 0, stream>>>(
        rowptr, eidx, (const half4v*)bufA, dinv, (half4v*)bufB);
    gemm_mfma<256, false><<<dim3(NPAD / 64, 4), 256, 0, stream>>>(
        bufB, W2t, b2, dinv, out);
}

// Round 9
// 321.646 us; speedup vs baseline: 1.4422x; 1.1707x over previous
//
#include <hip/hip_runtime.h>

constexpr int N = 50000;    // nodes
constexpr int E = 800000;   // edges
constexpr int NPAD = 50048; // padded to 64-row multiple for GEMM A tiles
constexpr int NB = (N + 255) / 256;   // 196 scan blocks

typedef _Float16 half8 __attribute__((ext_vector_type(8)));
typedef _Float16 half4v __attribute__((ext_vector_type(4)));
typedef float float4v __attribute__((ext_vector_type(4)));

// ---------------- degree / normalization / CSR ----------------
__global__ __launch_bounds__(256) void deg_kernel(const int* __restrict__ dst,
                                                  int* __restrict__ degI) {
    int e = blockIdx.x * 256 + threadIdx.x;
    if (e < E) atomicAdd(&degI[dst[e]], 1);
}

__global__ __launch_bounds__(256) void dinv_kernel(const int* __restrict__ degI,
                                                   float* __restrict__ dinv) {
    int v = blockIdx.x * 256 + threadIdx.x;
    if (v < N) dinv[v] = rsqrtf((float)degI[v] + 1.0f);   // +1 = self loop
}

// ---- 3-phase scan ----
__global__ __launch_bounds__(256) void scan1_kernel(const int* __restrict__ degI,
                                                    int* __restrict__ incl,
                                                    int* __restrict__ blockSums) {
    __shared__ int s[256];
    int t = threadIdx.x;
    int i = blockIdx.x * 256 + t;
    int d = (i < N) ? degI[i] : 0;
    s[t] = d;
    __syncthreads();
    for (int off = 1; off < 256; off <<= 1) {
        int v = s[t];
        int u = (t >= off) ? s[t - off] : 0;
        __syncthreads();
        s[t] = v + u;
        __syncthreads();
    }
    if (i < N) incl[i] = s[t];
    if (t == 255) blockSums[blockIdx.x] = s[255];
}

__global__ __launch_bounds__(256) void scan2_kernel(int* __restrict__ blockSums) {
    __shared__ int s[256];
    int t = threadIdx.x;
    int v = (t < NB) ? blockSums[t] : 0;
    s[t] = v;
    __syncthreads();
    for (int off = 1; off < 256; off <<= 1) {
        int a = s[t];
        int u = (t >= off) ? s[t - off] : 0;
        __syncthreads();
        s[t] = a + u;
        __syncthreads();
    }
    if (t < NB) blockSums[t] = s[t] - v;   // exclusive block offset
}

__global__ __launch_bounds__(256) void scan3_kernel(const int* __restrict__ degI,
                                                    const int* __restrict__ incl,
                                                    const int* __restrict__ blockSums,
                                                    int* __restrict__ rowptr,
                                                    int* __restrict__ cursor) {
    int i = blockIdx.x * 256 + threadIdx.x;
    if (i < N) {
        int e = blockSums[blockIdx.x] + incl[i] - degI[i];
        rowptr[i] = e;
        cursor[i] = e;
    }
    if (i == 0) rowptr[N] = E;
}

__global__ __launch_bounds__(256) void fill_kernel(const int* __restrict__ src,
                                                   const int* __restrict__ dst,
                                                   int* __restrict__ cursor,
                                                   int* __restrict__ eidx) {
    int e = blockIdx.x * 256 + threadIdx.x;
    if (e >= E) return;
    int d = dst[e];
    int pos = atomicAdd(&cursor[d], 1);
    eidx[pos] = src[e];
}

// ---------------- weight transpose+cast: Wt[n][k] = (f16) W[k][n] ----------------
template <int K>
__global__ __launch_bounds__(256) void wt_kernel(const float* __restrict__ W,
                                                 _Float16* __restrict__ Wt) {
    int idx = blockIdx.x * 256 + threadIdx.x;
    int k = idx & (K - 1);
    int n = idx >> (K == 128 ? 7 : 8);
    Wt[idx] = (_Float16)W[(size_t)k * 256 + n];
}

// ---------------- prescale: px = dinv[v] * x   (fp32 -> fp16, 128 ch) ----------------
__global__ __launch_bounds__(256) void prescale_kernel(const float4* __restrict__ x,
                                                       const float* __restrict__ dinv,
                                                       half4v* __restrict__ px) {
    int idx = blockIdx.x * 256 + threadIdx.x;
    if (idx >= N * 32) return;
    float dv = dinv[idx >> 5];
    float4 t = x[idx];
    half4v o;
    o[0] = (_Float16)(t.x * dv);
    o[1] = (_Float16)(t.y * dv);
    o[2] = (_Float16)(t.z * dv);
    o[3] = (_Float16)(t.w * dv);
    px[idx] = o;
}

// ---------------- gather-aggregate, 8-way MLP unroll (fp16 rows, fp32 accum) ------
template <int C4>
__global__ __launch_bounds__(256) void aggregate_f16(
    const int* __restrict__ rowptr, const int* __restrict__ eidx,
    const half4v* __restrict__ f, const float* __restrict__ dinv,
    half4v* __restrict__ q) {
    int v = blockIdx.x * (256 / C4) + threadIdx.x / C4;
    if (v >= N) return;
    int lane = threadIdx.x % C4;
    int beg = rowptr[v];
    int end = rowptr[v + 1];

    half4v sv = f[(size_t)v * C4 + lane];
    float a0 = (float)sv[0], a1 = (float)sv[1], a2 = (float)sv[2], a3 = (float)sv[3];

    int i = beg;
    for (; i + 8 <= end; i += 8) {
        int e0 = eidx[i + 0], e1 = eidx[i + 1], e2 = eidx[i + 2], e3 = eidx[i + 3];
        int e4 = eidx[i + 4], e5 = eidx[i + 5], e6 = eidx[i + 6], e7 = eidx[i + 7];
        half4v t0 = f[(size_t)e0 * C4 + lane];
        half4v t1 = f[(size_t)e1 * C4 + lane];
        half4v t2 = f[(size_t)e2 * C4 + lane];
        half4v t3 = f[(size_t)e3 * C4 + lane];
        half4v t4 = f[(size_t)e4 * C4 + lane];
        half4v t5 = f[(size_t)e5 * C4 + lane];
        half4v t6 = f[(size_t)e6 * C4 + lane];
        half4v t7 = f[(size_t)e7 * C4 + lane];
        a0 += ((float)t0[0] + (float)t1[0]) + ((float)t2[0] + (float)t3[0]) +
              ((float)t4[0] + (float)t5[0]) + ((float)t6[0] + (float)t7[0]);
        a1 += ((float)t0[1] + (float)t1[1]) + ((float)t2[1] + (float)t3[1]) +
              ((float)t4[1] + (float)t5[1]) + ((float)t6[1] + (float)t7[1]);
        a2 += ((float)t0[2] + (float)t1[2]) + ((float)t2[2] + (float)t3[2]) +
              ((float)t4[2] + (float)t5[2]) + ((float)t6[2] + (float)t7[2]);
        a3 += ((float)t0[3] + (float)t1[3]) + ((float)t2[3] + (float)t3[3]) +
              ((float)t4[3] + (float)t5[3]) + ((float)t6[3] + (float)t7[3]);
    }
    for (; i + 2 <= end; i += 2) {
        int e0 = eidx[i], e1 = eidx[i + 1];
        half4v t0 = f[(size_t)e0 * C4 + lane];
        half4v t1 = f[(size_t)e1 * C4 + lane];
        a0 += (float)t0[0] + (float)t1[0];
        a1 += (float)t0[1] + (float)t1[1];
        a2 += (float)t0[2] + (float)t1[2];
        a3 += (float)t0[3] + (float)t1[3];
    }
    if (i < end) {
        half4v t0 = f[(size_t)eidx[i] * C4 + lane];
        a0 += (float)t0[0];
        a1 += (float)t0[1];
        a2 += (float)t0[2];
        a3 += (float)t0[3];
    }

    float dv = dinv[v];
    half4v o;
    o[0] = (_Float16)(a0 * dv);
    o[1] = (_Float16)(a1 * dv);
    o[2] = (_Float16)(a2 * dv);
    o[3] = (_Float16)(a3 * dv);
    q[(size_t)v * C4 + lane] = o;
}

// ---------------- fp16 MFMA GEMM: A-frags in regs, Wt staged in LDS ----------------
// Block: 64 rows x 256 cols (4 col-chunks of 64). A row-major [NPAD,K] f16,
// Wt row-major [256,K] f16. A is read exactly once per block (all K in regs).
// FUSE1: out f16 = dinv[row]*relu(D+bias); else fp32 out = D+bias.
template <int K, bool FUSE1>
__global__ __launch_bounds__(256) void gemm_mfma(
    const _Float16* __restrict__ A, const _Float16* __restrict__ Wt,
    const float* __restrict__ bias, const float* __restrict__ dinv,
    void* __restrict__ outp) {
    constexpr int LSTR = K + 8;                 // halves; pad to spread LDS banks
    __shared__ _Float16 Bs[64 * LSTR];          // K=256: 33 KB, K=128: 17 KB

    const int tid = threadIdx.x;
    const int wave = tid >> 6;
    const int lane = tid & 63;
    const int m = lane & 15;
    const int quad = lane >> 4;
    const int rbase = blockIdx.x * 64 + wave * 16;
    const int row = rbase + m;

    // All A-fragments for this lane's row, whole K: independent global loads.
    half8 af[K / 32];
    {
        const half8* Arow = (const half8*)(A + (size_t)row * K);
#pragma unroll
        for (int i = 0; i < K / 32; ++i) af[i] = Arow[i * 4 + quad];
    }

    for (int cc = 0; cc < 4; ++cc) {
        const int colbase = cc * 64;
        if (cc) __syncthreads();
        // stage Wt rows [colbase, colbase+64) into LDS (16 B per thread per unit)
        {
            int col = tid >> 2;
            int sub = tid & 3;
            const half8* srcb = (const half8*)(Wt + (size_t)(colbase + col) * K);
            half8* dstb = (half8*)&Bs[col * LSTR];
#pragma unroll
            for (int u = 0; u < K / 32; ++u) dstb[sub + u * 4] = srcb[sub + u * 4];
        }
        __syncthreads();

        float4v acc[4] = {};
#pragma unroll
        for (int k0 = 0; k0 < K; k0 += 32) {
            half8 a = af[k0 >> 5];
#pragma unroll
            for (int c = 0; c < 4; ++c) {
                half8 b = *(const half8*)&Bs[(c * 16 + m) * LSTR + k0 + quad * 8];
                acc[c] = __builtin_amdgcn_mfma_f32_16x16x32_f16(a, b, acc[c], 0, 0, 0);
            }
        }

#pragma unroll
        for (int c = 0; c < 4; ++c) {
            int col = colbase + c * 16 + m;
            float bcol = bias[col];
#pragma unroll
            for (int r = 0; r < 4; ++r) {
                int orow = rbase + quad * 4 + r;   // C/D: col=lane&15, row=quad*4+reg
                if (orow < N) {
                    float val = acc[c][r] + bcol;
                    if (FUSE1) {
                        val = fmaxf(val, 0.f) * dinv[orow];
                        ((_Float16*)outp)[(size_t)orow * 256 + col] = (_Float16)val;
                    } else {
                        ((float*)outp)[(size_t)orow * 256 + col] = val;
                    }
                }
            }
        }
    }
}

extern "C" void kernel_launch(void* const* d_in, const int* in_sizes, int n_in,
                              void* d_out, int out_size, void* d_ws, size_t ws_size,
                              hipStream_t stream) {
    const float* x  = (const float*)d_in[0];
    const int* edge = (const int*)d_in[1];
    const int* src  = edge;
    const int* dst  = edge + E;
    const float* W1 = (const float*)d_in[2];
    const float* b1 = (const float*)d_in[3];
    const float* W2 = (const float*)d_in[4];
    const float* b2 = (const float*)d_in[5];
    float* out = (float*)d_out;

    _Float16* bufA = (_Float16*)d_ws;
    _Float16* bufB = bufA + (size_t)NPAD * 256;
    float* dinv    = (float*)(bufB + (size_t)NPAD * 256);
    int* degI      = (int*)(dinv + N);
    int* rowptr    = degI + N;
    int* cursor    = rowptr + (N + 1);
    int* eidx      = cursor + N;
    _Float16* W1t  = (_Float16*)(eidx + E);
    _Float16* W2t  = W1t + 256 * 128;
    int* blockSums = (int*)(W2t + 256 * 256);

    // ---- CSR + normalization ----
    hipMemsetAsync(degI, 0, N * sizeof(int), stream);
    deg_kernel<<<(E + 255) / 256, 256, 0, stream>>>(dst, degI);
    dinv_kernel<<<(N + 255) / 256, 256, 0, stream>>>(degI, dinv);
    scan1_kernel<<<NB, 256, 0, stream>>>(degI, cursor, blockSums);
    scan2_kernel<<<1, 256, 0, stream>>>(blockSums);
    scan3_kernel<<<NB, 256, 0, stream>>>(degI, cursor, blockSums, rowptr, cursor);
    fill_kernel<<<(E + 255) / 256, 256, 0, stream>>>(src, dst, cursor, eidx);

    // ---- weights to f16 transposed ----
    wt_kernel<128><<<(256 * 128) / 256, 256, 0, stream>>>(W1, W1t);
    wt_kernel<256><<<(256 * 256) / 256, 256, 0, stream>>>(W2, W2t);

    // ---- layer 1:  q1 = Ahat x (aggregate first), h1p = dinv*relu(q1@W1+b1) ----
    prescale_kernel<<<(N * 32 + 255) / 256, 256, 0, stream>>>(
        (const float4*)x, dinv, (half4v*)bufA);
    aggregate_f16<32><<<(N + 7) / 8, 256, 0, stream>>>(
        rowptr, eidx, (const half4v*)bufA, dinv, (half4v*)bufB);
    gemm_mfma<128, true><<<NPAD / 64, 256, 0, stream>>>(
        bufB, W1t, b1, dinv, bufA);

    // ---- layer 2:  q2 = Ahat h1, out = q2@W2 + b2 ----
    aggregate_f16<64><<<(N + 3) / 4, 256, 0, stream>>>(
        rowptr, eidx, (const half4v*)bufA, dinv, (half4v*)bufB);
    gemm_mfma<256, false><<<NPAD / 64, 256, 0, stream>>>(
        bufB, W2t, b2, dinv, out);
}